// Round 15
// baseline (57.861 us; speedup 1.0000x reference)
//
#include <hip/hip_runtime.h>
#include <hip/hip_bf16.h>

#define N_TOK 9216
#define C_IN  128
#define CI    64
#define L2E   1.44269504088896340736f

typedef __bf16 bf16x8 __attribute__((ext_vector_type(8)));
typedef unsigned short u16;
typedef u16 u16x4 __attribute__((ext_vector_type(4)));
typedef u16 u16x8 __attribute__((ext_vector_type(8)));
typedef unsigned u32x4 __attribute__((ext_vector_type(4)));
typedef float f32x4 __attribute__((ext_vector_type(4)));

static __device__ __forceinline__ u16 f2bf(float f) {
  return __builtin_bit_cast(u16, __float2bfloat16(f));   // RNE, HW cvt path
}
static __device__ __forceinline__ float bf2f(u16 b) {
  unsigned u = ((unsigned)b) << 16;
  return __builtin_bit_cast(float, u);
}
static __device__ __forceinline__ bf16x8 pack8(const float* f) {
  u16x8 t;
#pragma unroll
  for (int j = 0; j < 8; ++j) t[j] = f2bf(f[j]);
  return __builtin_bit_cast(bf16x8, t);
}
static __device__ __forceinline__ bf16x8 load_bf8(const u16* p) {
  u32x4 v = *(const u32x4*)p;
  return __builtin_bit_cast(bf16x8, v);
}
// async global -> LDS, 16B per lane; LDS dest is wave-uniform base + lane*16
static __device__ __forceinline__ void gload_lds16(const void* g, void* l) {
  __builtin_amdgcn_global_load_lds(
      (const __attribute__((address_space(1))) void*)g,
      (__attribute__((address_space(3))) void*)l, 16, 0, 0);
}

#define MFMA16(a, b, c) __builtin_amdgcn_mfma_f32_16x16x32_bf16((a), (b), (c), 0, 0, 0)

// ---------------------------------------------------------------------------
// K1: QKV projections -> FRAGMENT-ORDER buffers. One matrix per blockIdx.y.
// theta PRE-SCALED by L2E (k2 uses exp2). (R13-passing version)
// ---------------------------------------------------------------------------
__global__ __launch_bounds__(256) void k1_proj(
    const float* __restrict__ x,
    const float* __restrict__ tw, const float* __restrict__ tb,
    const float* __restrict__ pw, const float* __restrict__ pb,
    const float* __restrict__ gw, const float* __restrict__ gb,
    u16* __restrict__ thetaF, u16* __restrict__ phiF, u16* __restrict__ vF)
{
  __shared__ u16 sbuf[64 * 72];
  const int tid = threadIdx.x;
  const int w = tid >> 6, lane = tid & 63;
  const int lr = lane & 15, lg = lane >> 4;
  const int p0 = blockIdx.x * 64;
  const int m = blockIdx.y;

  bf16x8 bf[4][4];
#pragma unroll
  for (int nt = 0; nt < 4; ++nt) {
    const int p = p0 + nt * 16 + lr;
#pragma unroll
    for (int kc = 0; kc < 4; ++kc) {
      const int c0 = kc * 32 + lg * 8;
      float f[8];
#pragma unroll
      for (int j = 0; j < 8; ++j) f[j] = x[(c0 + j) * N_TOK + p];
      bf[nt][kc] = pack8(f);
    }
  }

  const float* Wm = (m == 0) ? tw : (m == 1) ? pw : gw;
  const float* Bm = (m == 0) ? tb : (m == 1) ? pb : gb;

  bf16x8 af[4];
#pragma unroll
  for (int kc = 0; kc < 4; ++kc) {
    const float* src = Wm + (w * 16 + lr) * C_IN + kc * 32 + lg * 8;
    float f[8];
#pragma unroll
    for (int j = 0; j < 8; ++j) f[j] = src[j];
    af[kc] = pack8(f);
  }
  f32x4 acc[4];
#pragma unroll
  for (int nt = 0; nt < 4; ++nt) acc[nt] = f32x4{0.f, 0.f, 0.f, 0.f};
#pragma unroll
  for (int kc = 0; kc < 4; ++kc)
#pragma unroll
    for (int nt = 0; nt < 4; ++nt)
      acc[nt] = MFMA16(af[kc], bf[nt][kc], acc[nt]);

  float bias[4];
#pragma unroll
  for (int r = 0; r < 4; ++r) bias[r] = Bm[w * 16 + lg * 4 + r];

  const float oscale = (m == 0) ? L2E : 1.0f;   // pre-scale theta by log2(e)

  if (m < 2) {
    // stage sbuf[p_local][d], row stride 72
#pragma unroll
    for (int nt = 0; nt < 4; ++nt)
#pragma unroll
      for (int r = 0; r < 4; ++r)
        sbuf[(nt * 16 + lr) * 72 + (w * 16 + lg * 4 + r)] =
            f2bf((acc[nt][r] + bias[r]) * oscale);
    __syncthreads();
    if (m == 0) {
#pragma unroll
      for (int e = 0; e < 2; ++e) {
        const int ch = tid * 2 + e;
        const int ln = ch & 63, c = (ch >> 6) & 1, qt = ch >> 7;
        const int ql = qt * 16 + (ln & 15), d = c * 32 + (ln >> 4) * 8;
        u32x4 v = *(const u32x4*)&sbuf[ql * 72 + d];
        *(u32x4*)&thetaF[(((size_t)(p0 / 16 + qt) * 2 + c) * 64 + ln) * 8] = v;
      }
    } else {
#pragma unroll
      for (int e = 0; e < 2; ++e) {
        const int ch = tid * 2 + e;
        const int ln = ch & 63, i = (ch >> 6) & 3, t = ch >> 8;
        const int kl = t * 32 + (i >> 1) * 16 + (ln & 15);
        const int d = (i & 1) * 32 + (ln >> 4) * 8;
        u32x4 v = *(const u32x4*)&sbuf[kl * 72 + d];
        *(u32x4*)&phiF[(((size_t)(p0 / 32 + t) * 4 + i) * 64 + ln) * 8] = v;
      }
    }
  } else {
    // stage sbuf[d][kv_local], row stride 72
#pragma unroll
    for (int nt = 0; nt < 4; ++nt)
#pragma unroll
      for (int r = 0; r < 4; ++r)
        sbuf[(w * 16 + lg * 4 + r) * 72 + nt * 16 + lr] = f2bf(acc[nt][r] + bias[r]);
    __syncthreads();
#pragma unroll
    for (int e = 0; e < 2; ++e) {
      const int ch = tid * 2 + e;
      const int ln = ch & 63, n = (ch >> 6) & 3, t = ch >> 8;
      const int d = n * 16 + (ln & 15), g4 = (ln >> 4) * 4;
      u16x4 lo = *(const u16x4*)&sbuf[d * 72 + t * 32 + g4];
      u16x4 hi = *(const u16x4*)&sbuf[d * 72 + t * 32 + 16 + g4];
      u16x8 v;
#pragma unroll
      for (int j = 0; j < 4; ++j) { v[j] = lo[j]; v[4 + j] = hi[j]; }
      *(u16x8*)&vF[(((size_t)(p0 / 32 + t) * 4 + n) * 64 + ln) * 8] = v;
    }
  }
}

// ---------------------------------------------------------------------------
// K2: flash attention partial with COUNTED-VMCNT 2-DEEP PIPELINE (T3/T4).
// Stage tile T+2 while computing T; raw s_barrier + vmcnt(4) keeps T+2's
// loads in flight across barriers (only T+1's, issued a full iter earlier,
// are drained). lgkmcnt(0)+sched_barrier before the read-protection barrier
// (rule #18). 32 q-rows/wave; K AND V in LDS (32 KB dbuf); p = exp2(s);
// row-sums via ones-MFMA; setprio around MFMA clusters.
// Grid = 72 q-tiles(128q) x SPL.
// ---------------------------------------------------------------------------
template <int SPL>
__global__ __launch_bounds__(256) void k2_flash(
    const u16* __restrict__ thetaF, const u16* __restrict__ phiF,
    const u16* __restrict__ vF,
    u16* __restrict__ Opart, float* __restrict__ Lpart)
{
  __shared__ u16 kvbuf[2][16][512];  // 32 KB: frags 0-7 K (h*4+i), 8-15 V
  const int tid = threadIdx.x;
  const int w = tid >> 6, lane = tid & 63;
  const int lr = lane & 15, g = lane >> 4;
  const int ks = blockIdx.x & (SPL - 1);
  const int qt = blockIdx.x / SPL;
  const int q0 = qt * 128 + w * 32;
  const int NT64 = (N_TOK / SPL) / 64;   // 9 (SPL=16) / 18 (SPL=8)
  const int t64base = ks * NT64;

  bf16x8 qb[2][2];
#pragma unroll
  for (int qs = 0; qs < 2; ++qs)
#pragma unroll
    for (int c = 0; c < 2; ++c)
      qb[qs][c] = load_bf8(&thetaF[(((size_t)(q0 / 16 + qs) * 2 + c) * 64 + lane) * 8]);

  f32x4 o[2][4], o4[2];
#pragma unroll
  for (int qs = 0; qs < 2; ++qs) {
#pragma unroll
    for (int n = 0; n < 4; ++n) o[qs][n] = f32x4{0.f, 0.f, 0.f, 0.f};
    o4[qs] = f32x4{0.f, 0.f, 0.f, 0.f};
  }

  u16x8 onesw;
#pragma unroll
  for (int j = 0; j < 8; ++j) onesw[j] = 0x3F80;   // bf16 1.0
  const bf16x8 ones = __builtin_bit_cast(bf16x8, onesw);

  // staging: wave w stages frags fbase..fbase+3 (w<2: K half w, w>=2: V half w&1)
  const u16* sbase = (w < 2) ? phiF : vF;
  const int fbase = w * 4;
  const int sub = w & 1;

#define STAGE(T, buf)                                                          \
  {                                                                            \
    const u16* gp = sbase + (size_t)(2 * (t64base + (T)) + sub) * 2048 +       \
                    lane * 8;                                                  \
    gload_lds16(gp,        &kvbuf[buf][fbase][0]);                             \
    gload_lds16(gp + 512,  &kvbuf[buf][fbase + 1][0]);                         \
    gload_lds16(gp + 1024, &kvbuf[buf][fbase + 2][0]);                         \
    gload_lds16(gp + 1536, &kvbuf[buf][fbase + 3][0]);                         \
  }

  // prologue: stage tiles 0 and 1; wait only tile 0 (4 oldest of 8)
  STAGE(0, 0);
  STAGE(1, 1);
  asm volatile("s_waitcnt vmcnt(4)" ::: "memory");
  __builtin_amdgcn_s_barrier();            // all waves' tile-0 loads done
  __builtin_amdgcn_sched_barrier(0);

  for (int T = 0; T < NT64; ++T) {
    const int cur = T & 1;

#pragma unroll
    for (int h = 0; h < 2; ++h) {
      const bf16x8 ka0 = load_bf8(&kvbuf[cur][h * 4 + 0][lane * 8]);
      const bf16x8 ka1 = load_bf8(&kvbuf[cur][h * 4 + 1][lane * 8]);
      const bf16x8 ka2 = load_bf8(&kvbuf[cur][h * 4 + 2][lane * 8]);
      const bf16x8 ka3 = load_bf8(&kvbuf[cur][h * 4 + 3][lane * 8]);
      bf16x8 va[4];
#pragma unroll
      for (int n = 0; n < 4; ++n) va[n] = load_bf8(&kvbuf[cur][8 + h * 4 + n][lane * 8]);

#pragma unroll
      for (int qs = 0; qs < 2; ++qs) {
        f32x4 s0 = f32x4{0.f, 0.f, 0.f, 0.f}, s1 = f32x4{0.f, 0.f, 0.f, 0.f};
        __builtin_amdgcn_s_setprio(1);
        s0 = MFMA16(ka0, qb[qs][0], s0); s0 = MFMA16(ka1, qb[qs][1], s0);
        s1 = MFMA16(ka2, qb[qs][0], s1); s1 = MFMA16(ka3, qb[qs][1], s1);
        __builtin_amdgcn_s_setprio(0);

        float p0v[4], p1v[4];
#pragma unroll
        for (int r = 0; r < 4; ++r) {
          p0v[r] = __builtin_amdgcn_exp2f(s0[r]);
          p1v[r] = __builtin_amdgcn_exp2f(s1[r]);
        }
        u16x8 pw;
#pragma unroll
        for (int r = 0; r < 4; ++r) { pw[r] = f2bf(p0v[r]); pw[4 + r] = f2bf(p1v[r]); }
        const bf16x8 pb = __builtin_bit_cast(bf16x8, pw);
        __builtin_amdgcn_s_setprio(1);
#pragma unroll
        for (int n = 0; n < 4; ++n) o[qs][n] = MFMA16(va[n], pb, o[qs][n]);
        o4[qs] = MFMA16(ones, pb, o4[qs]);   // row-sums per q-subtile
        __builtin_amdgcn_s_setprio(0);
      }
    }

    if (T + 1 < NT64) {
      // all our ds_reads of kvbuf[cur] must have COMPLETED before another
      // wave's staging overwrites it (rule #18: lgkm drain + sched fence)
      asm volatile("s_waitcnt lgkmcnt(0)" ::: "memory");
      __builtin_amdgcn_sched_barrier(0);
      __builtin_amdgcn_s_barrier();          // all waves done reading buf[cur]
      __builtin_amdgcn_sched_barrier(0);
      if (T + 2 < NT64) {
        STAGE(T + 2, cur);                   // overwrite the buffer just freed
        asm volatile("s_waitcnt vmcnt(4)" ::: "memory");  // T+1's 4 oldest done
      } else {
        asm volatile("s_waitcnt vmcnt(0)" ::: "memory");  // drain last tile
      }
      __builtin_amdgcn_s_barrier();          // tile T+1 staged for all waves
      __builtin_amdgcn_sched_barrier(0);
    }
  }

  const int qg = ks * N_TOK + q0;
#pragma unroll
  for (int qs = 0; qs < 2; ++qs) {
#pragma unroll
    for (int n = 0; n < 4; ++n) {
      u16x4 ov;
#pragma unroll
      for (int r = 0; r < 4; ++r) ov[r] = f2bf(o[qs][n][r]);
      *(u16x4*)&Opart[(size_t)(qg + qs * 16 + lr) * CI + n * 16 + 4 * g] = ov;
    }
    if (lane < 16) Lpart[qg + qs * 16 + lr] = o4[qs][0];
  }
}

// ---------------------------------------------------------------------------
// K3 (fused): combine SPL kv-split partials + 2nd softmax -> y in LDS ->
// output GEMM + bias + residual. (R13-passing version)
// ---------------------------------------------------------------------------
template <int SPL>
__global__ __launch_bounds__(256) void k3_fused(
    const u16* __restrict__ Opart, const float* __restrict__ Lpart,
    const float* __restrict__ ow, const float* __restrict__ ob,
    const float* __restrict__ x, float* __restrict__ out)
{
  __shared__ u16 ylds[32 * 72];
  const int tid = threadIdx.x;
  const int w = tid >> 6, lane = tid & 63;
  const int lr = lane & 15, lg = lane >> 4;
  const int p0 = blockIdx.x * 32;

  // ---- phase 1: combine + 2nd softmax, one wave per q-row, 8 rows/wave ----
  for (int it = 0; it < 8; ++it) {
    const int qloc = w * 8 + it;
    const int q = p0 + qloc;

    float L = 0.f, acc = 0.f;
#pragma unroll
    for (int k = 0; k < SPL; ++k) {
      L += Lpart[k * N_TOK + q];
      acc += bf2f(Opart[(size_t)(k * N_TOK + q) * CI + lane]);
    }
    const float ypre = acc / L;

    float mx = ypre;
#pragma unroll
    for (int off = 1; off <= 32; off <<= 1) mx = fmaxf(mx, __shfl_xor(mx, off, 64));
    const float e = __builtin_amdgcn_exp2f((ypre - mx) * L2E);
    float s = e;
#pragma unroll
    for (int off = 1; off <= 32; off <<= 1) s += __shfl_xor(s, off, 64);
    ylds[qloc * 72 + lane] = f2bf(e / s);
  }
  __syncthreads();

  // ---- phase 2: output GEMM (y from LDS stride 72) ----
  bf16x8 yb[2][2];
#pragma unroll
  for (int nt = 0; nt < 2; ++nt)
#pragma unroll
    for (int kc = 0; kc < 2; ++kc)
      yb[nt][kc] = load_bf8(&ylds[(nt * 16 + lr) * 72 + kc * 32 + lg * 8]);

#pragma unroll
  for (int mt = 0; mt < 2; ++mt) {
    bf16x8 af[2];
#pragma unroll
    for (int kc = 0; kc < 2; ++kc) {
      const float* src = ow + (w * 32 + mt * 16 + lr) * CI + kc * 32 + lg * 8;
      float f[8];
#pragma unroll
      for (int j = 0; j < 8; ++j) f[j] = src[j];
      af[kc] = pack8(f);
    }
#pragma unroll
    for (int nt = 0; nt < 2; ++nt) {
      f32x4 acc = f32x4{0.f, 0.f, 0.f, 0.f};
      acc = MFMA16(af[0], yb[nt][0], acc);
      acc = MFMA16(af[1], yb[nt][1], acc);
#pragma unroll
      for (int r = 0; r < 4; ++r) {
        const int c = w * 32 + mt * 16 + lg * 4 + r;
        const int p = p0 + nt * 16 + lr;
        out[(size_t)c * N_TOK + p] = acc[r] + ob[c] + x[(size_t)c * N_TOK + p];
      }
    }
  }
}

extern "C" void kernel_launch(void* const* d_in, const int* in_sizes, int n_in,
                              void* d_out, int out_size, void* d_ws, size_t ws_size,
                              hipStream_t stream) {
  const float* x  = (const float*)d_in[0];
  const float* tw = (const float*)d_in[1];
  const float* tb = (const float*)d_in[2];
  const float* pw = (const float*)d_in[3];
  const float* pb = (const float*)d_in[4];
  const float* gw = (const float*)d_in[5];
  const float* gb = (const float*)d_in[6];
  const float* ow = (const float*)d_in[7];
  const float* ob = (const float*)d_in[8];
  float* out = (float*)d_out;

  char* ws = (char*)d_ws;
  u16* thetaF = (u16*)(ws);
  u16* phiF   = (u16*)(ws + 1179648);
  u16* vF     = (u16*)(ws + 2 * 1179648);
  u16* Op     = (u16*)(ws + 4 * 1179648);   // keep R12 offsets (slot 3 unused)

  const size_t opOff = 4 * 1179648;
  const size_t need16 = opOff + (size_t)16 * N_TOK * CI * 2 + (size_t)16 * N_TOK * 4;

  hipLaunchKernelGGL(k1_proj, dim3(144, 3), dim3(256), 0, stream,
                     x, tw, tb, pw, pb, gw, gb, thetaF, phiF, vF);

  if (ws_size >= need16) {
    float* Lp = (float*)(ws + opOff + (size_t)16 * N_TOK * CI * 2);
    hipLaunchKernelGGL((k2_flash<16>), dim3(72 * 16), dim3(256), 0, stream,
                       thetaF, phiF, vF, Op, Lp);
    hipLaunchKernelGGL((k3_fused<16>), dim3(288), dim3(256), 0, stream,
                       Op, Lp, ow, ob, x, out);
  } else {
    float* Lp = (float*)(ws + opOff + (size_t)8 * N_TOK * CI * 2);
    hipLaunchKernelGGL((k2_flash<8>), dim3(72 * 8), dim3(256), 0, stream,
                       thetaF, phiF, vF, Op, Lp);
    hipLaunchKernelGGL((k3_fused<8>), dim3(288), dim3(256), 0, stream,
                       Op, Lp, ow, ob, x, out);
  }
}

// Round 16
// 51.775 us; speedup vs baseline: 1.1176x; 1.1176x over previous
//
#include <hip/hip_runtime.h>
#include <hip/hip_bf16.h>

#define N_TOK 9216
#define C_IN  128
#define CI    64
#define L2E   1.44269504088896340736f

typedef __bf16 bf16x8 __attribute__((ext_vector_type(8)));
typedef unsigned short u16;
typedef u16 u16x4 __attribute__((ext_vector_type(4)));
typedef u16 u16x8 __attribute__((ext_vector_type(8)));
typedef unsigned u32x4 __attribute__((ext_vector_type(4)));
typedef float f32x4 __attribute__((ext_vector_type(4)));

static __device__ __forceinline__ u16 f2bf(float f) {
  return __builtin_bit_cast(u16, __float2bfloat16(f));   // RNE, HW cvt path
}
static __device__ __forceinline__ float bf2f(u16 b) {
  unsigned u = ((unsigned)b) << 16;
  return __builtin_bit_cast(float, u);
}
static __device__ __forceinline__ bf16x8 pack8(const float* f) {
  u16x8 t;
#pragma unroll
  for (int j = 0; j < 8; ++j) t[j] = f2bf(f[j]);
  return __builtin_bit_cast(bf16x8, t);
}
static __device__ __forceinline__ bf16x8 load_bf8(const u16* p) {
  u32x4 v = *(const u32x4*)p;
  return __builtin_bit_cast(bf16x8, v);
}
// async global -> LDS, 16B per lane; LDS dest is wave-uniform base + lane*16
static __device__ __forceinline__ void gload_lds16(const void* g, void* l) {
  __builtin_amdgcn_global_load_lds(
      (const __attribute__((address_space(1))) void*)g,
      (__attribute__((address_space(3))) void*)l, 16, 0, 0);
}

#define MFMA16(a, b, c) __builtin_amdgcn_mfma_f32_16x16x32_bf16((a), (b), (c), 0, 0, 0)

// ---------------------------------------------------------------------------
// K1: QKV projections -> FRAGMENT-ORDER buffers. One matrix per blockIdx.y.
// theta PRE-SCALED by L2E (k2 uses exp2). (R13-passing version)
// ---------------------------------------------------------------------------
__global__ __launch_bounds__(256) void k1_proj(
    const float* __restrict__ x,
    const float* __restrict__ tw, const float* __restrict__ tb,
    const float* __restrict__ pw, const float* __restrict__ pb,
    const float* __restrict__ gw, const float* __restrict__ gb,
    u16* __restrict__ thetaF, u16* __restrict__ phiF, u16* __restrict__ vF)
{
  __shared__ u16 sbuf[64 * 72];
  const int tid = threadIdx.x;
  const int w = tid >> 6, lane = tid & 63;
  const int lr = lane & 15, lg = lane >> 4;
  const int p0 = blockIdx.x * 64;
  const int m = blockIdx.y;

  bf16x8 bf[4][4];
#pragma unroll
  for (int nt = 0; nt < 4; ++nt) {
    const int p = p0 + nt * 16 + lr;
#pragma unroll
    for (int kc = 0; kc < 4; ++kc) {
      const int c0 = kc * 32 + lg * 8;
      float f[8];
#pragma unroll
      for (int j = 0; j < 8; ++j) f[j] = x[(c0 + j) * N_TOK + p];
      bf[nt][kc] = pack8(f);
    }
  }

  const float* Wm = (m == 0) ? tw : (m == 1) ? pw : gw;
  const float* Bm = (m == 0) ? tb : (m == 1) ? pb : gb;

  bf16x8 af[4];
#pragma unroll
  for (int kc = 0; kc < 4; ++kc) {
    const float* src = Wm + (w * 16 + lr) * C_IN + kc * 32 + lg * 8;
    float f[8];
#pragma unroll
    for (int j = 0; j < 8; ++j) f[j] = src[j];
    af[kc] = pack8(f);
  }
  f32x4 acc[4];
#pragma unroll
  for (int nt = 0; nt < 4; ++nt) acc[nt] = f32x4{0.f, 0.f, 0.f, 0.f};
#pragma unroll
  for (int kc = 0; kc < 4; ++kc)
#pragma unroll
    for (int nt = 0; nt < 4; ++nt)
      acc[nt] = MFMA16(af[kc], bf[nt][kc], acc[nt]);

  float bias[4];
#pragma unroll
  for (int r = 0; r < 4; ++r) bias[r] = Bm[w * 16 + lg * 4 + r];

  const float oscale = (m == 0) ? L2E : 1.0f;   // pre-scale theta by log2(e)

  if (m < 2) {
    // stage sbuf[p_local][d], row stride 72
#pragma unroll
    for (int nt = 0; nt < 4; ++nt)
#pragma unroll
      for (int r = 0; r < 4; ++r)
        sbuf[(nt * 16 + lr) * 72 + (w * 16 + lg * 4 + r)] =
            f2bf((acc[nt][r] + bias[r]) * oscale);
    __syncthreads();
    if (m == 0) {
#pragma unroll
      for (int e = 0; e < 2; ++e) {
        const int ch = tid * 2 + e;
        const int ln = ch & 63, c = (ch >> 6) & 1, qt = ch >> 7;
        const int ql = qt * 16 + (ln & 15), d = c * 32 + (ln >> 4) * 8;
        u32x4 v = *(const u32x4*)&sbuf[ql * 72 + d];
        *(u32x4*)&thetaF[(((size_t)(p0 / 16 + qt) * 2 + c) * 64 + ln) * 8] = v;
      }
    } else {
#pragma unroll
      for (int e = 0; e < 2; ++e) {
        const int ch = tid * 2 + e;
        const int ln = ch & 63, i = (ch >> 6) & 3, t = ch >> 8;
        const int kl = t * 32 + (i >> 1) * 16 + (ln & 15);
        const int d = (i & 1) * 32 + (ln >> 4) * 8;
        u32x4 v = *(const u32x4*)&sbuf[kl * 72 + d];
        *(u32x4*)&phiF[(((size_t)(p0 / 32 + t) * 4 + i) * 64 + ln) * 8] = v;
      }
    }
  } else {
    // stage sbuf[d][kv_local], row stride 72
#pragma unroll
    for (int nt = 0; nt < 4; ++nt)
#pragma unroll
      for (int r = 0; r < 4; ++r)
        sbuf[(w * 16 + lg * 4 + r) * 72 + nt * 16 + lr] = f2bf(acc[nt][r] + bias[r]);
    __syncthreads();
#pragma unroll
    for (int e = 0; e < 2; ++e) {
      const int ch = tid * 2 + e;
      const int ln = ch & 63, n = (ch >> 6) & 3, t = ch >> 8;
      const int d = n * 16 + (ln & 15), g4 = (ln >> 4) * 4;
      u16x4 lo = *(const u16x4*)&sbuf[d * 72 + t * 32 + g4];
      u16x4 hi = *(const u16x4*)&sbuf[d * 72 + t * 32 + 16 + g4];
      u16x8 v;
#pragma unroll
      for (int j = 0; j < 4; ++j) { v[j] = lo[j]; v[4 + j] = hi[j]; }
      *(u16x8*)&vF[(((size_t)(p0 / 32 + t) * 4 + n) * 64 + ln) * 8] = v;
    }
  }
}

// ---------------------------------------------------------------------------
// K2: flash attention partial (R13-passing body: __syncthreads per tile,
// setprio around MFMA clusters). 32 q-rows/wave; K AND V staged in LDS
// (32 KB dbuf); p = exp2(s); row-sums via ones-MFMA.
// Grid = 72 q-tiles(128q) x SPL.
// ---------------------------------------------------------------------------
template <int SPL>
__global__ __launch_bounds__(256) void k2_flash(
    const u16* __restrict__ thetaF, const u16* __restrict__ phiF,
    const u16* __restrict__ vF,
    u16* __restrict__ Opart, float* __restrict__ Lpart)
{
  __shared__ u16 kvbuf[2][16][512];  // 32 KB: frags 0-7 K (h*4+i), 8-15 V
  const int tid = threadIdx.x;
  const int w = tid >> 6, lane = tid & 63;
  const int lr = lane & 15, g = lane >> 4;
  const int ks = blockIdx.x & (SPL - 1);
  const int qt = blockIdx.x / SPL;
  const int q0 = qt * 128 + w * 32;
  const int NT64 = (N_TOK / SPL) / 64;
  const int t64base = ks * NT64;

  bf16x8 qb[2][2];
#pragma unroll
  for (int qs = 0; qs < 2; ++qs)
#pragma unroll
    for (int c = 0; c < 2; ++c)
      qb[qs][c] = load_bf8(&thetaF[(((size_t)(q0 / 16 + qs) * 2 + c) * 64 + lane) * 8]);

  f32x4 o[2][4], o4[2];
#pragma unroll
  for (int qs = 0; qs < 2; ++qs) {
#pragma unroll
    for (int n = 0; n < 4; ++n) o[qs][n] = f32x4{0.f, 0.f, 0.f, 0.f};
    o4[qs] = f32x4{0.f, 0.f, 0.f, 0.f};
  }

  u16x8 onesw;
#pragma unroll
  for (int j = 0; j < 8; ++j) onesw[j] = 0x3F80;   // bf16 1.0
  const bf16x8 ones = __builtin_bit_cast(bf16x8, onesw);

  // staging: wave w stages frags fbase..fbase+3 (w<2: K half w, w>=2: V half w&1)
  const u16* sbase = (w < 2) ? phiF : vF;
  const int fbase = w * 4;
  const int sub = w & 1;

#define STAGE(T, buf)                                                          \
  {                                                                            \
    const u16* gp = sbase + (size_t)(2 * (t64base + (T)) + sub) * 2048 +       \
                    lane * 8;                                                  \
    gload_lds16(gp,        &kvbuf[buf][fbase][0]);                             \
    gload_lds16(gp + 512,  &kvbuf[buf][fbase + 1][0]);                         \
    gload_lds16(gp + 1024, &kvbuf[buf][fbase + 2][0]);                         \
    gload_lds16(gp + 1536, &kvbuf[buf][fbase + 3][0]);                         \
  }

  STAGE(0, 0);
  __syncthreads();

  int cur = 0;
  for (int T = 0; T < NT64; ++T) {
    if (T + 1 < NT64) STAGE(T + 1, cur ^ 1);

#pragma unroll
    for (int h = 0; h < 2; ++h) {
      const bf16x8 ka0 = load_bf8(&kvbuf[cur][h * 4 + 0][lane * 8]);
      const bf16x8 ka1 = load_bf8(&kvbuf[cur][h * 4 + 1][lane * 8]);
      const bf16x8 ka2 = load_bf8(&kvbuf[cur][h * 4 + 2][lane * 8]);
      const bf16x8 ka3 = load_bf8(&kvbuf[cur][h * 4 + 3][lane * 8]);
      bf16x8 va[4];
#pragma unroll
      for (int n = 0; n < 4; ++n) va[n] = load_bf8(&kvbuf[cur][8 + h * 4 + n][lane * 8]);

#pragma unroll
      for (int qs = 0; qs < 2; ++qs) {
        f32x4 s0 = f32x4{0.f, 0.f, 0.f, 0.f}, s1 = f32x4{0.f, 0.f, 0.f, 0.f};
        __builtin_amdgcn_s_setprio(1);
        s0 = MFMA16(ka0, qb[qs][0], s0); s0 = MFMA16(ka1, qb[qs][1], s0);
        s1 = MFMA16(ka2, qb[qs][0], s1); s1 = MFMA16(ka3, qb[qs][1], s1);
        __builtin_amdgcn_s_setprio(0);

        float p0v[4], p1v[4];
#pragma unroll
        for (int r = 0; r < 4; ++r) {
          p0v[r] = __builtin_amdgcn_exp2f(s0[r]);
          p1v[r] = __builtin_amdgcn_exp2f(s1[r]);
        }
        u16x8 pw;
#pragma unroll
        for (int r = 0; r < 4; ++r) { pw[r] = f2bf(p0v[r]); pw[4 + r] = f2bf(p1v[r]); }
        const bf16x8 pb = __builtin_bit_cast(bf16x8, pw);
        __builtin_amdgcn_s_setprio(1);
#pragma unroll
        for (int n = 0; n < 4; ++n) o[qs][n] = MFMA16(va[n], pb, o[qs][n]);
        o4[qs] = MFMA16(ones, pb, o4[qs]);   // row-sums per q-subtile
        __builtin_amdgcn_s_setprio(0);
      }
    }

    __syncthreads();   // drains vmcnt (staging done) + orders LDS reuse
    cur ^= 1;
  }

  const int qg = ks * N_TOK + q0;
#pragma unroll
  for (int qs = 0; qs < 2; ++qs) {
#pragma unroll
    for (int n = 0; n < 4; ++n) {
      u16x4 ov;
#pragma unroll
      for (int r = 0; r < 4; ++r) ov[r] = f2bf(o[qs][n][r]);
      *(u16x4*)&Opart[(size_t)(qg + qs * 16 + lr) * CI + n * 16 + 4 * g] = ov;
    }
    if (lane < 16) Lpart[qg + qs * 16 + lr] = o4[qs][0];
  }
}

// ---------------------------------------------------------------------------
// K3 (fused): PARALLEL combine (8 threads per token: tok=tid>>3, 8 d each;
// 3-step shfl_xor reduction within the 8-lane group) + 2nd softmax -> y in
// LDS -> output GEMM + bias + residual. 288 blocks x 32 tokens.
// ---------------------------------------------------------------------------
template <int SPL>
__global__ __launch_bounds__(256) void k3_fused(
    const u16* __restrict__ Opart, const float* __restrict__ Lpart,
    const float* __restrict__ ow, const float* __restrict__ ob,
    const float* __restrict__ x, float* __restrict__ out)
{
  __shared__ u16 ylds[32 * 72];
  const int tid = threadIdx.x;
  const int w = tid >> 6, lane = tid & 63;
  const int lr = lane & 15, lg = lane >> 4;
  const int p0 = blockIdx.x * 32;

  // ---- phase 1: combine + 2nd softmax, 8 threads per token ----
  {
    const int tok = tid >> 3, dj = (tid & 7) * 8;
    const int q = p0 + tok;

    float L = 0.f;
    float acc[8];
#pragma unroll
    for (int j = 0; j < 8; ++j) acc[j] = 0.f;
#pragma unroll
    for (int k = 0; k < SPL; ++k) {
      L += Lpart[k * N_TOK + q];
      u32x4 v = *(const u32x4*)&Opart[(size_t)(k * N_TOK + q) * CI + dj];
      const u16* pv = (const u16*)&v;
#pragma unroll
      for (int j = 0; j < 8; ++j) acc[j] += bf2f(pv[j]);
    }
    const float invL = 1.f / L;
    float ypre[8];
#pragma unroll
    for (int j = 0; j < 8; ++j) ypre[j] = acc[j] * invL;

    float mx = ypre[0];
#pragma unroll
    for (int j = 1; j < 8; ++j) mx = fmaxf(mx, ypre[j]);
    mx = fmaxf(mx, __shfl_xor(mx, 1, 64));
    mx = fmaxf(mx, __shfl_xor(mx, 2, 64));
    mx = fmaxf(mx, __shfl_xor(mx, 4, 64));

    float e[8], s = 0.f;
#pragma unroll
    for (int j = 0; j < 8; ++j) {
      e[j] = __builtin_amdgcn_exp2f((ypre[j] - mx) * L2E);
      s += e[j];
    }
    s += __shfl_xor(s, 1, 64);
    s += __shfl_xor(s, 2, 64);
    s += __shfl_xor(s, 4, 64);
    const float inv = 1.f / s;

    u16x8 yv;
#pragma unroll
    for (int j = 0; j < 8; ++j) yv[j] = f2bf(e[j] * inv);
    *(u16x8*)&ylds[tok * 72 + dj] = yv;   // 16B store, row stride 144B (16-aligned)
  }
  __syncthreads();

  // ---- phase 2: output GEMM (y from LDS stride 72) ----
  bf16x8 yb[2][2];
#pragma unroll
  for (int nt = 0; nt < 2; ++nt)
#pragma unroll
    for (int kc = 0; kc < 2; ++kc)
      yb[nt][kc] = load_bf8(&ylds[(nt * 16 + lr) * 72 + kc * 32 + lg * 8]);

#pragma unroll
  for (int mt = 0; mt < 2; ++mt) {
    bf16x8 af[2];
#pragma unroll
    for (int kc = 0; kc < 2; ++kc) {
      const float* src = ow + (w * 32 + mt * 16 + lr) * CI + kc * 32 + lg * 8;
      float f[8];
#pragma unroll
      for (int j = 0; j < 8; ++j) f[j] = src[j];
      af[kc] = pack8(f);
    }
#pragma unroll
    for (int nt = 0; nt < 2; ++nt) {
      f32x4 acc = f32x4{0.f, 0.f, 0.f, 0.f};
      acc = MFMA16(af[0], yb[nt][0], acc);
      acc = MFMA16(af[1], yb[nt][1], acc);
#pragma unroll
      for (int r = 0; r < 4; ++r) {
        const int c = w * 32 + mt * 16 + lg * 4 + r;
        const int p = p0 + nt * 16 + lr;
        out[(size_t)c * N_TOK + p] = acc[r] + ob[c] + x[(size_t)c * N_TOK + p];
      }
    }
  }
}

extern "C" void kernel_launch(void* const* d_in, const int* in_sizes, int n_in,
                              void* d_out, int out_size, void* d_ws, size_t ws_size,
                              hipStream_t stream) {
  const float* x  = (const float*)d_in[0];
  const float* tw = (const float*)d_in[1];
  const float* tb = (const float*)d_in[2];
  const float* pw = (const float*)d_in[3];
  const float* pb = (const float*)d_in[4];
  const float* gw = (const float*)d_in[5];
  const float* gb = (const float*)d_in[6];
  const float* ow = (const float*)d_in[7];
  const float* ob = (const float*)d_in[8];
  float* out = (float*)d_out;

  char* ws = (char*)d_ws;
  u16* thetaF = (u16*)(ws);
  u16* phiF   = (u16*)(ws + 1179648);
  u16* vF     = (u16*)(ws + 2 * 1179648);
  u16* Op     = (u16*)(ws + 4 * 1179648);   // keep R12 offsets (slot 3 unused)

  const size_t opOff = 4 * 1179648;
  const size_t need16 = opOff + (size_t)16 * N_TOK * CI * 2 + (size_t)16 * N_TOK * 4;

  hipLaunchKernelGGL(k1_proj, dim3(144, 3), dim3(256), 0, stream,
                     x, tw, tb, pw, pb, gw, gb, thetaF, phiF, vF);

  if (ws_size >= need16) {
    float* Lp = (float*)(ws + opOff + (size_t)16 * N_TOK * CI * 2);
    hipLaunchKernelGGL((k2_flash<16>), dim3(72 * 16), dim3(256), 0, stream,
                       thetaF, phiF, vF, Op, Lp);
    hipLaunchKernelGGL((k3_fused<16>), dim3(288), dim3(256), 0, stream,
                       Op, Lp, ow, ob, x, out);
  } else {
    float* Lp = (float*)(ws + opOff + (size_t)8 * N_TOK * CI * 2);
    hipLaunchKernelGGL((k2_flash<8>), dim3(72 * 8), dim3(256), 0, stream,
                       thetaF, phiF, vF, Op, Lp);
    hipLaunchKernelGGL((k3_fused<8>), dim3(288), dim3(256), 0, stream,
                       Op, Lp, ow, ob, x, out);
  }
}

// Round 17
// 51.343 us; speedup vs baseline: 1.1270x; 1.0084x over previous
//
#include <hip/hip_runtime.h>
#include <hip/hip_bf16.h>

#define N_TOK 9216
#define C_IN  128
#define CI    64
#define L2E   1.44269504088896340736f

typedef __bf16 bf16x8 __attribute__((ext_vector_type(8)));
typedef unsigned short u16;
typedef u16 u16x4 __attribute__((ext_vector_type(4)));
typedef u16 u16x8 __attribute__((ext_vector_type(8)));
typedef unsigned u32x4 __attribute__((ext_vector_type(4)));
typedef float f32x4 __attribute__((ext_vector_type(4)));

static __device__ __forceinline__ u16 f2bf(float f) {
  return __builtin_bit_cast(u16, __float2bfloat16(f));   // RNE, HW cvt path
}
static __device__ __forceinline__ float bf2f(u16 b) {
  unsigned u = ((unsigned)b) << 16;
  return __builtin_bit_cast(float, u);
}
static __device__ __forceinline__ bf16x8 pack8(const float* f) {
  u16x8 t;
#pragma unroll
  for (int j = 0; j < 8; ++j) t[j] = f2bf(f[j]);
  return __builtin_bit_cast(bf16x8, t);
}
static __device__ __forceinline__ bf16x8 load_bf8(const u16* p) {
  u32x4 v = *(const u32x4*)p;
  return __builtin_bit_cast(bf16x8, v);
}
// async global -> LDS, 16B per lane; LDS dest is wave-uniform base + lane*16
static __device__ __forceinline__ void gload_lds16(const void* g, void* l) {
  __builtin_amdgcn_global_load_lds(
      (const __attribute__((address_space(1))) void*)g,
      (__attribute__((address_space(3))) void*)l, 16, 0, 0);
}

#define MFMA16(a, b, c) __builtin_amdgcn_mfma_f32_16x16x32_bf16((a), (b), (c), 0, 0, 0)

// ---------------------------------------------------------------------------
// K1: QKV projections -> FRAGMENT-ORDER buffers. One matrix per blockIdx.y.
// theta PRE-SCALED by L2E (k2 uses exp2). (R15-passing version)
// ---------------------------------------------------------------------------
__global__ __launch_bounds__(256) void k1_proj(
    const float* __restrict__ x,
    const float* __restrict__ tw, const float* __restrict__ tb,
    const float* __restrict__ pw, const float* __restrict__ pb,
    const float* __restrict__ gw, const float* __restrict__ gb,
    u16* __restrict__ thetaF, u16* __restrict__ phiF, u16* __restrict__ vF)
{
  __shared__ u16 sbuf[64 * 72];
  const int tid = threadIdx.x;
  const int w = tid >> 6, lane = tid & 63;
  const int lr = lane & 15, lg = lane >> 4;
  const int p0 = blockIdx.x * 64;
  const int m = blockIdx.y;

  bf16x8 bf[4][4];
#pragma unroll
  for (int nt = 0; nt < 4; ++nt) {
    const int p = p0 + nt * 16 + lr;
#pragma unroll
    for (int kc = 0; kc < 4; ++kc) {
      const int c0 = kc * 32 + lg * 8;
      float f[8];
#pragma unroll
      for (int j = 0; j < 8; ++j) f[j] = x[(c0 + j) * N_TOK + p];
      bf[nt][kc] = pack8(f);
    }
  }

  const float* Wm = (m == 0) ? tw : (m == 1) ? pw : gw;
  const float* Bm = (m == 0) ? tb : (m == 1) ? pb : gb;

  bf16x8 af[4];
#pragma unroll
  for (int kc = 0; kc < 4; ++kc) {
    const float* src = Wm + (w * 16 + lr) * C_IN + kc * 32 + lg * 8;
    float f[8];
#pragma unroll
    for (int j = 0; j < 8; ++j) f[j] = src[j];
    af[kc] = pack8(f);
  }
  f32x4 acc[4];
#pragma unroll
  for (int nt = 0; nt < 4; ++nt) acc[nt] = f32x4{0.f, 0.f, 0.f, 0.f};
#pragma unroll
  for (int kc = 0; kc < 4; ++kc)
#pragma unroll
    for (int nt = 0; nt < 4; ++nt)
      acc[nt] = MFMA16(af[kc], bf[nt][kc], acc[nt]);

  float bias[4];
#pragma unroll
  for (int r = 0; r < 4; ++r) bias[r] = Bm[w * 16 + lg * 4 + r];

  const float oscale = (m == 0) ? L2E : 1.0f;   // pre-scale theta by log2(e)

  if (m < 2) {
    // stage sbuf[p_local][d], row stride 72
#pragma unroll
    for (int nt = 0; nt < 4; ++nt)
#pragma unroll
      for (int r = 0; r < 4; ++r)
        sbuf[(nt * 16 + lr) * 72 + (w * 16 + lg * 4 + r)] =
            f2bf((acc[nt][r] + bias[r]) * oscale);
    __syncthreads();
    if (m == 0) {
#pragma unroll
      for (int e = 0; e < 2; ++e) {
        const int ch = tid * 2 + e;
        const int ln = ch & 63, c = (ch >> 6) & 1, qt = ch >> 7;
        const int ql = qt * 16 + (ln & 15), d = c * 32 + (ln >> 4) * 8;
        u32x4 v = *(const u32x4*)&sbuf[ql * 72 + d];
        *(u32x4*)&thetaF[(((size_t)(p0 / 16 + qt) * 2 + c) * 64 + ln) * 8] = v;
      }
    } else {
#pragma unroll
      for (int e = 0; e < 2; ++e) {
        const int ch = tid * 2 + e;
        const int ln = ch & 63, i = (ch >> 6) & 3, t = ch >> 8;
        const int kl = t * 32 + (i >> 1) * 16 + (ln & 15);
        const int d = (i & 1) * 32 + (ln >> 4) * 8;
        u32x4 v = *(const u32x4*)&sbuf[kl * 72 + d];
        *(u32x4*)&phiF[(((size_t)(p0 / 32 + t) * 4 + i) * 64 + ln) * 8] = v;
      }
    }
  } else {
    // stage sbuf[d][kv_local], row stride 72
#pragma unroll
    for (int nt = 0; nt < 4; ++nt)
#pragma unroll
      for (int r = 0; r < 4; ++r)
        sbuf[(w * 16 + lg * 4 + r) * 72 + nt * 16 + lr] = f2bf(acc[nt][r] + bias[r]);
    __syncthreads();
#pragma unroll
    for (int e = 0; e < 2; ++e) {
      const int ch = tid * 2 + e;
      const int ln = ch & 63, n = (ch >> 6) & 3, t = ch >> 8;
      const int d = n * 16 + (ln & 15), g4 = (ln >> 4) * 4;
      u16x4 lo = *(const u16x4*)&sbuf[d * 72 + t * 32 + g4];
      u16x4 hi = *(const u16x4*)&sbuf[d * 72 + t * 32 + 16 + g4];
      u16x8 v;
#pragma unroll
      for (int j = 0; j < 4; ++j) { v[j] = lo[j]; v[4 + j] = hi[j]; }
      *(u16x8*)&vF[(((size_t)(p0 / 32 + t) * 4 + n) * 64 + ln) * 8] = v;
    }
  }
}

// ---------------------------------------------------------------------------
// K2: flash attention partial. 32 q-rows/wave; K staged in LDS (16 KB dbuf,
// R10-proven staging: wave w stages frags f0=2w,f0+1); V streamed per-wave
// from L2 in fragment order (340 MB at 32q), issued at iteration top.
// p = exp2(s); row-sums via ones-MFMA; setprio around MFMA clusters.
// Grid = 72 q-tiles(128q) x SPL (SPL=16 -> 1152 blocks, fixes R10's
// occupancy deficit; K-only LDS halves port traffic vs R12).
// ---------------------------------------------------------------------------
template <int SPL>
__global__ __launch_bounds__(256) void k2_flash(
    const u16* __restrict__ thetaF, const u16* __restrict__ phiF,
    const u16* __restrict__ vF,
    u16* __restrict__ Opart, float* __restrict__ Lpart)
{
  __shared__ u16 kvbuf[2][8][512];  // 16 KB: K frags only, frag = h*4+i
  const int tid = threadIdx.x;
  const int w = tid >> 6, lane = tid & 63;
  const int lr = lane & 15, g = lane >> 4;
  const int ks = blockIdx.x & (SPL - 1);
  const int qt = blockIdx.x / SPL;
  const int q0 = qt * 128 + w * 32;
  const int NT64 = (N_TOK / SPL) / 64;   // 9 (SPL=16) / 18 (SPL=8)
  const int t64base = ks * NT64;

  bf16x8 qb[2][2];
#pragma unroll
  for (int qs = 0; qs < 2; ++qs)
#pragma unroll
    for (int c = 0; c < 2; ++c)
      qb[qs][c] = load_bf8(&thetaF[(((size_t)(q0 / 16 + qs) * 2 + c) * 64 + lane) * 8]);

  f32x4 o[2][4], o4[2];
#pragma unroll
  for (int qs = 0; qs < 2; ++qs) {
#pragma unroll
    for (int n = 0; n < 4; ++n) o[qs][n] = f32x4{0.f, 0.f, 0.f, 0.f};
    o4[qs] = f32x4{0.f, 0.f, 0.f, 0.f};
  }

  u16x8 onesw;
#pragma unroll
  for (int j = 0; j < 8; ++j) onesw[j] = 0x3F80;   // bf16 1.0
  const bf16x8 ones = __builtin_bit_cast(bf16x8, onesw);

  // K staging: wave w stages frags f0=2w, f0+1 (frag = h*4+i; h=w>>1, i=f0&3)
  const int f0 = 2 * w;
  const size_t kgoff = (size_t)(f0 & 3) * 512 + lane * 8;
  const int hW = w >> 1;

#define STAGE(T, buf)                                                         \
  {                                                                           \
    const u16* gp = phiF + (size_t)(2 * (t64base + (T)) + hW) * 2048 + kgoff; \
    gload_lds16(gp, &kvbuf[buf][f0][0]);                                      \
    gload_lds16(gp + 512, &kvbuf[buf][f0 + 1][0]);                            \
  }

  STAGE(0, 0);
  __syncthreads();

  int cur = 0;
  for (int T = 0; T < NT64; ++T) {
    // V fragments for both halves from L2, fragment-order (issued early)
    bf16x8 va[2][4];
    const u16* pV = vF + (size_t)(2 * (t64base + T)) * 2048 + lane * 8;
#pragma unroll
    for (int h = 0; h < 2; ++h)
#pragma unroll
      for (int n = 0; n < 4; ++n)
        va[h][n] = load_bf8(pV + (size_t)(h * 4 + n) * 512);

    if (T + 1 < NT64) STAGE(T + 1, cur ^ 1);

#pragma unroll
    for (int h = 0; h < 2; ++h) {
      const bf16x8 ka0 = load_bf8(&kvbuf[cur][h * 4 + 0][lane * 8]);
      const bf16x8 ka1 = load_bf8(&kvbuf[cur][h * 4 + 1][lane * 8]);
      const bf16x8 ka2 = load_bf8(&kvbuf[cur][h * 4 + 2][lane * 8]);
      const bf16x8 ka3 = load_bf8(&kvbuf[cur][h * 4 + 3][lane * 8]);

#pragma unroll
      for (int qs = 0; qs < 2; ++qs) {
        f32x4 s0 = f32x4{0.f, 0.f, 0.f, 0.f}, s1 = f32x4{0.f, 0.f, 0.f, 0.f};
        __builtin_amdgcn_s_setprio(1);
        s0 = MFMA16(ka0, qb[qs][0], s0); s0 = MFMA16(ka1, qb[qs][1], s0);
        s1 = MFMA16(ka2, qb[qs][0], s1); s1 = MFMA16(ka3, qb[qs][1], s1);
        __builtin_amdgcn_s_setprio(0);

        float p0v[4], p1v[4];
#pragma unroll
        for (int r = 0; r < 4; ++r) {
          p0v[r] = __builtin_amdgcn_exp2f(s0[r]);
          p1v[r] = __builtin_amdgcn_exp2f(s1[r]);
        }
        u16x8 pw;
#pragma unroll
        for (int r = 0; r < 4; ++r) { pw[r] = f2bf(p0v[r]); pw[4 + r] = f2bf(p1v[r]); }
        const bf16x8 pb = __builtin_bit_cast(bf16x8, pw);
        __builtin_amdgcn_s_setprio(1);
#pragma unroll
        for (int n = 0; n < 4; ++n) o[qs][n] = MFMA16(va[h][n], pb, o[qs][n]);
        o4[qs] = MFMA16(ones, pb, o4[qs]);   // row-sums per q-subtile
        __builtin_amdgcn_s_setprio(0);
      }
    }

    __syncthreads();   // drains vmcnt (staging done) + orders LDS reuse
    cur ^= 1;
  }

  const int qg = ks * N_TOK + q0;
#pragma unroll
  for (int qs = 0; qs < 2; ++qs) {
#pragma unroll
    for (int n = 0; n < 4; ++n) {
      u16x4 ov;
#pragma unroll
      for (int r = 0; r < 4; ++r) ov[r] = f2bf(o[qs][n][r]);
      *(u16x4*)&Opart[(size_t)(qg + qs * 16 + lr) * CI + n * 16 + 4 * g] = ov;
    }
    if (lane < 16) Lpart[qg + qs * 16 + lr] = o4[qs][0];
  }
}

// ---------------------------------------------------------------------------
// K3 (fused): PARALLEL combine (8 threads per token) + 2nd softmax -> y in
// LDS -> output GEMM + bias + residual. (R15-passing version)
// ---------------------------------------------------------------------------
template <int SPL>
__global__ __launch_bounds__(256) void k3_fused(
    const u16* __restrict__ Opart, const float* __restrict__ Lpart,
    const float* __restrict__ ow, const float* __restrict__ ob,
    const float* __restrict__ x, float* __restrict__ out)
{
  __shared__ u16 ylds[32 * 72];
  const int tid = threadIdx.x;
  const int w = tid >> 6, lane = tid & 63;
  const int lr = lane & 15, lg = lane >> 4;
  const int p0 = blockIdx.x * 32;

  // ---- phase 1: combine + 2nd softmax, 8 threads per token ----
  {
    const int tok = tid >> 3, dj = (tid & 7) * 8;
    const int q = p0 + tok;

    float L = 0.f;
    float acc[8];
#pragma unroll
    for (int j = 0; j < 8; ++j) acc[j] = 0.f;
#pragma unroll
    for (int k = 0; k < SPL; ++k) {
      L += Lpart[k * N_TOK + q];
      u32x4 v = *(const u32x4*)&Opart[(size_t)(k * N_TOK + q) * CI + dj];
      const u16* pv = (const u16*)&v;
#pragma unroll
      for (int j = 0; j < 8; ++j) acc[j] += bf2f(pv[j]);
    }
    const float invL = 1.f / L;
    float ypre[8];
#pragma unroll
    for (int j = 0; j < 8; ++j) ypre[j] = acc[j] * invL;

    float mx = ypre[0];
#pragma unroll
    for (int j = 1; j < 8; ++j) mx = fmaxf(mx, ypre[j]);
    mx = fmaxf(mx, __shfl_xor(mx, 1, 64));
    mx = fmaxf(mx, __shfl_xor(mx, 2, 64));
    mx = fmaxf(mx, __shfl_xor(mx, 4, 64));

    float e[8], s = 0.f;
#pragma unroll
    for (int j = 0; j < 8; ++j) {
      e[j] = __builtin_amdgcn_exp2f((ypre[j] - mx) * L2E);
      s += e[j];
    }
    s += __shfl_xor(s, 1, 64);
    s += __shfl_xor(s, 2, 64);
    s += __shfl_xor(s, 4, 64);
    const float inv = 1.f / s;

    u16x8 yv;
#pragma unroll
    for (int j = 0; j < 8; ++j) yv[j] = f2bf(e[j] * inv);
    *(u16x8*)&ylds[tok * 72 + dj] = yv;   // 16B store, row stride 144B (16-aligned)
  }
  __syncthreads();

  // ---- phase 2: output GEMM (y from LDS stride 72) ----
  bf16x8 yb[2][2];
#pragma unroll
  for (int nt = 0; nt < 2; ++nt)
#pragma unroll
    for (int kc = 0; kc < 2; ++kc)
      yb[nt][kc] = load_bf8(&ylds[(nt * 16 + lr) * 72 + kc * 32 + lg * 8]);

#pragma unroll
  for (int mt = 0; mt < 2; ++mt) {
    bf16x8 af[2];
#pragma unroll
    for (int kc = 0; kc < 2; ++kc) {
      const float* src = ow + (w * 32 + mt * 16 + lr) * CI + kc * 32 + lg * 8;
      float f[8];
#pragma unroll
      for (int j = 0; j < 8; ++j) f[j] = src[j];
      af[kc] = pack8(f);
    }
#pragma unroll
    for (int nt = 0; nt < 2; ++nt) {
      f32x4 acc = f32x4{0.f, 0.f, 0.f, 0.f};
      acc = MFMA16(af[0], yb[nt][0], acc);
      acc = MFMA16(af[1], yb[nt][1], acc);
#pragma unroll
      for (int r = 0; r < 4; ++r) {
        const int c = w * 32 + mt * 16 + lg * 4 + r;
        const int p = p0 + nt * 16 + lr;
        out[(size_t)c * N_TOK + p] = acc[r] + ob[c] + x[(size_t)c * N_TOK + p];
      }
    }
  }
}

extern "C" void kernel_launch(void* const* d_in, const int* in_sizes, int n_in,
                              void* d_out, int out_size, void* d_ws, size_t ws_size,
                              hipStream_t stream) {
  const float* x  = (const float*)d_in[0];
  const float* tw = (const float*)d_in[1];
  const float* tb = (const float*)d_in[2];
  const float* pw = (const float*)d_in[3];
  const float* pb = (const float*)d_in[4];
  const float* gw = (const float*)d_in[5];
  const float* gb = (const float*)d_in[6];
  const float* ow = (const float*)d_in[7];
  const float* ob = (const float*)d_in[8];
  float* out = (float*)d_out;

  char* ws = (char*)d_ws;
  u16* thetaF = (u16*)(ws);
  u16* phiF   = (u16*)(ws + 1179648);
  u16* vF     = (u16*)(ws + 2 * 1179648);
  u16* Op     = (u16*)(ws + 4 * 1179648);   // keep R12 offsets (slot 3 unused)

  const size_t opOff = 4 * 1179648;
  const size_t need16 = opOff + (size_t)16 * N_TOK * CI * 2 + (size_t)16 * N_TOK * 4;

  hipLaunchKernelGGL(k1_proj, dim3(144, 3), dim3(256), 0, stream,
                     x, tw, tb, pw, pb, gw, gb, thetaF, phiF, vF);

  if (ws_size >= need16) {
    float* Lp = (float*)(ws + opOff + (size_t)16 * N_TOK * CI * 2);
    hipLaunchKernelGGL((k2_flash<16>), dim3(72 * 16), dim3(256), 0, stream,
                       thetaF, phiF, vF, Op, Lp);
    hipLaunchKernelGGL((k3_fused<16>), dim3(288), dim3(256), 0, stream,
                       Op, Lp, ow, ob, x, out);
  } else {
    float* Lp = (float*)(ws + opOff + (size_t)8 * N_TOK * CI * 2);
    hipLaunchKernelGGL((k2_flash<8>), dim3(72 * 8), dim3(256), 0, stream,
                       thetaF, phiF, vF, Op, Lp);
    hipLaunchKernelGGL((k3_fused<8>), dim3(288), dim3(256), 0, stream,
                       Op, Lp, ow, ob, x, out);
  }
}

// Round 18
// 49.794 us; speedup vs baseline: 1.1620x; 1.0311x over previous
//
#include <hip/hip_runtime.h>
#include <hip/hip_bf16.h>

#define N_TOK 9216
#define C_IN  128
#define CI    64
#define L2E   1.44269504088896340736f

typedef __bf16 bf16x8 __attribute__((ext_vector_type(8)));
typedef unsigned short u16;
typedef u16 u16x4 __attribute__((ext_vector_type(4)));
typedef u16 u16x8 __attribute__((ext_vector_type(8)));
typedef unsigned u32x4 __attribute__((ext_vector_type(4)));
typedef float f32x4 __attribute__((ext_vector_type(4)));

static __device__ __forceinline__ u16 f2bf(float f) {
  return __builtin_bit_cast(u16, __float2bfloat16(f));   // RNE, HW cvt path
}
static __device__ __forceinline__ float bf2f(u16 b) {
  unsigned u = ((unsigned)b) << 16;
  return __builtin_bit_cast(float, u);
}
static __device__ __forceinline__ bf16x8 pack8(const float* f) {
  u16x8 t;
#pragma unroll
  for (int j = 0; j < 8; ++j) t[j] = f2bf(f[j]);
  return __builtin_bit_cast(bf16x8, t);
}
static __device__ __forceinline__ bf16x8 load_bf8(const u16* p) {
  u32x4 v = *(const u32x4*)p;
  return __builtin_bit_cast(bf16x8, v);
}
// async global -> LDS, 16B per lane; LDS dest is wave-uniform base + lane*16
static __device__ __forceinline__ void gload_lds16(const void* g, void* l) {
  __builtin_amdgcn_global_load_lds(
      (const __attribute__((address_space(1))) void*)g,
      (__attribute__((address_space(3))) void*)l, 16, 0, 0);
}

#define MFMA16(a, b, c) __builtin_amdgcn_mfma_f32_16x16x32_bf16((a), (b), (c), 0, 0, 0)

// ---------------------------------------------------------------------------
// K1: QKV projections -> FRAGMENT-ORDER buffers. One matrix per blockIdx.y.
// theta PRE-SCALED by L2E (k2 uses exp2). (R16-passing version)
// ---------------------------------------------------------------------------
__global__ __launch_bounds__(256) void k1_proj(
    const float* __restrict__ x,
    const float* __restrict__ tw, const float* __restrict__ tb,
    const float* __restrict__ pw, const float* __restrict__ pb,
    const float* __restrict__ gw, const float* __restrict__ gb,
    u16* __restrict__ thetaF, u16* __restrict__ phiF, u16* __restrict__ vF)
{
  __shared__ u16 sbuf[64 * 72];
  const int tid = threadIdx.x;
  const int w = tid >> 6, lane = tid & 63;
  const int lr = lane & 15, lg = lane >> 4;
  const int p0 = blockIdx.x * 64;
  const int m = blockIdx.y;

  bf16x8 bf[4][4];
#pragma unroll
  for (int nt = 0; nt < 4; ++nt) {
    const int p = p0 + nt * 16 + lr;
#pragma unroll
    for (int kc = 0; kc < 4; ++kc) {
      const int c0 = kc * 32 + lg * 8;
      float f[8];
#pragma unroll
      for (int j = 0; j < 8; ++j) f[j] = x[(c0 + j) * N_TOK + p];
      bf[nt][kc] = pack8(f);
    }
  }

  const float* Wm = (m == 0) ? tw : (m == 1) ? pw : gw;
  const float* Bm = (m == 0) ? tb : (m == 1) ? pb : gb;

  bf16x8 af[4];
#pragma unroll
  for (int kc = 0; kc < 4; ++kc) {
    const float* src = Wm + (w * 16 + lr) * C_IN + kc * 32 + lg * 8;
    float f[8];
#pragma unroll
    for (int j = 0; j < 8; ++j) f[j] = src[j];
    af[kc] = pack8(f);
  }
  f32x4 acc[4];
#pragma unroll
  for (int nt = 0; nt < 4; ++nt) acc[nt] = f32x4{0.f, 0.f, 0.f, 0.f};
#pragma unroll
  for (int kc = 0; kc < 4; ++kc)
#pragma unroll
    for (int nt = 0; nt < 4; ++nt)
      acc[nt] = MFMA16(af[kc], bf[nt][kc], acc[nt]);

  float bias[4];
#pragma unroll
  for (int r = 0; r < 4; ++r) bias[r] = Bm[w * 16 + lg * 4 + r];

  const float oscale = (m == 0) ? L2E : 1.0f;   // pre-scale theta by log2(e)

  if (m < 2) {
    // stage sbuf[p_local][d], row stride 72
#pragma unroll
    for (int nt = 0; nt < 4; ++nt)
#pragma unroll
      for (int r = 0; r < 4; ++r)
        sbuf[(nt * 16 + lr) * 72 + (w * 16 + lg * 4 + r)] =
            f2bf((acc[nt][r] + bias[r]) * oscale);
    __syncthreads();
    if (m == 0) {
#pragma unroll
      for (int e = 0; e < 2; ++e) {
        const int ch = tid * 2 + e;
        const int ln = ch & 63, c = (ch >> 6) & 1, qt = ch >> 7;
        const int ql = qt * 16 + (ln & 15), d = c * 32 + (ln >> 4) * 8;
        u32x4 v = *(const u32x4*)&sbuf[ql * 72 + d];
        *(u32x4*)&thetaF[(((size_t)(p0 / 16 + qt) * 2 + c) * 64 + ln) * 8] = v;
      }
    } else {
#pragma unroll
      for (int e = 0; e < 2; ++e) {
        const int ch = tid * 2 + e;
        const int ln = ch & 63, i = (ch >> 6) & 3, t = ch >> 8;
        const int kl = t * 32 + (i >> 1) * 16 + (ln & 15);
        const int d = (i & 1) * 32 + (ln >> 4) * 8;
        u32x4 v = *(const u32x4*)&sbuf[kl * 72 + d];
        *(u32x4*)&phiF[(((size_t)(p0 / 32 + t) * 4 + i) * 64 + ln) * 8] = v;
      }
    }
  } else {
    // stage sbuf[d][kv_local], row stride 72
#pragma unroll
    for (int nt = 0; nt < 4; ++nt)
#pragma unroll
      for (int r = 0; r < 4; ++r)
        sbuf[(w * 16 + lg * 4 + r) * 72 + nt * 16 + lr] = f2bf(acc[nt][r] + bias[r]);
    __syncthreads();
#pragma unroll
    for (int e = 0; e < 2; ++e) {
      const int ch = tid * 2 + e;
      const int ln = ch & 63, n = (ch >> 6) & 3, t = ch >> 8;
      const int d = n * 16 + (ln & 15), g4 = (ln >> 4) * 4;
      u16x4 lo = *(const u16x4*)&sbuf[d * 72 + t * 32 + g4];
      u16x4 hi = *(const u16x4*)&sbuf[d * 72 + t * 32 + 16 + g4];
      u16x8 v;
#pragma unroll
      for (int j = 0; j < 4; ++j) { v[j] = lo[j]; v[4 + j] = hi[j]; }
      *(u16x8*)&vF[(((size_t)(p0 / 32 + t) * 4 + n) * 64 + ln) * 8] = v;
    }
  }
}

// ---------------------------------------------------------------------------
// K2: flash attention partial. 32 q-rows/wave; K staged in LDS (16 KB dbuf,
// wave w stages frags f0=2w,f0+1); V streamed per-wave from L2 per half
// (va[4] live -> ~16 fewer VGPR than both-halves). p = exp2(s); row-sums via
// ones-MFMA; setprio around MFMA clusters.
// Grid = 72 q-tiles(128q) x SPL (SPL=24 -> 1728 blocks, 6.75/CU: raises the
// grid occupancy cap from 18 to 27 waves/CU — k2 is latency-stalled and wave
// supply is its one proven lever).
// ---------------------------------------------------------------------------
template <int SPL>
__global__ __launch_bounds__(256) void k2_flash(
    const u16* __restrict__ thetaF, const u16* __restrict__ phiF,
    const u16* __restrict__ vF,
    u16* __restrict__ Opart, float* __restrict__ Lpart)
{
  __shared__ u16 kvbuf[2][8][512];  // 16 KB: K frags only, frag = h*4+i
  const int tid = threadIdx.x;
  const int w = tid >> 6, lane = tid & 63;
  const int lr = lane & 15, g = lane >> 4;
  const int ks = blockIdx.x % SPL;
  const int qt = blockIdx.x / SPL;
  const int q0 = qt * 128 + w * 32;
  const int NT64 = (N_TOK / SPL) / 64;   // 6 (SPL=24) / 18 (SPL=8)
  const int t64base = ks * NT64;

  bf16x8 qb[2][2];
#pragma unroll
  for (int qs = 0; qs < 2; ++qs)
#pragma unroll
    for (int c = 0; c < 2; ++c)
      qb[qs][c] = load_bf8(&thetaF[(((size_t)(q0 / 16 + qs) * 2 + c) * 64 + lane) * 8]);

  f32x4 o[2][4], o4[2];
#pragma unroll
  for (int qs = 0; qs < 2; ++qs) {
#pragma unroll
    for (int n = 0; n < 4; ++n) o[qs][n] = f32x4{0.f, 0.f, 0.f, 0.f};
    o4[qs] = f32x4{0.f, 0.f, 0.f, 0.f};
  }

  u16x8 onesw;
#pragma unroll
  for (int j = 0; j < 8; ++j) onesw[j] = 0x3F80;   // bf16 1.0
  const bf16x8 ones = __builtin_bit_cast(bf16x8, onesw);

  // K staging: wave w stages frags f0=2w, f0+1 (frag = h*4+i; h=w>>1, i=f0&3)
  const int f0 = 2 * w;
  const size_t kgoff = (size_t)(f0 & 3) * 512 + lane * 8;
  const int hW = w >> 1;

#define STAGE(T, buf)                                                         \
  {                                                                           \
    const u16* gp = phiF + (size_t)(2 * (t64base + (T)) + hW) * 2048 + kgoff; \
    gload_lds16(gp, &kvbuf[buf][f0][0]);                                      \
    gload_lds16(gp + 512, &kvbuf[buf][f0 + 1][0]);                            \
  }

  STAGE(0, 0);
  __syncthreads();

  int cur = 0;
  for (int T = 0; T < NT64; ++T) {
    const u16* pV = vF + (size_t)(2 * (t64base + T)) * 2048 + lane * 8;

    if (T + 1 < NT64) STAGE(T + 1, cur ^ 1);

#pragma unroll
    for (int h = 0; h < 2; ++h) {
      // V for this half from L2, fragment-order (issued before K reads)
      bf16x8 va[4];
#pragma unroll
      for (int n = 0; n < 4; ++n)
        va[n] = load_bf8(pV + (size_t)(h * 4 + n) * 512);

      const bf16x8 ka0 = load_bf8(&kvbuf[cur][h * 4 + 0][lane * 8]);
      const bf16x8 ka1 = load_bf8(&kvbuf[cur][h * 4 + 1][lane * 8]);
      const bf16x8 ka2 = load_bf8(&kvbuf[cur][h * 4 + 2][lane * 8]);
      const bf16x8 ka3 = load_bf8(&kvbuf[cur][h * 4 + 3][lane * 8]);

#pragma unroll
      for (int qs = 0; qs < 2; ++qs) {
        f32x4 s0 = f32x4{0.f, 0.f, 0.f, 0.f}, s1 = f32x4{0.f, 0.f, 0.f, 0.f};
        __builtin_amdgcn_s_setprio(1);
        s0 = MFMA16(ka0, qb[qs][0], s0); s0 = MFMA16(ka1, qb[qs][1], s0);
        s1 = MFMA16(ka2, qb[qs][0], s1); s1 = MFMA16(ka3, qb[qs][1], s1);
        __builtin_amdgcn_s_setprio(0);

        float p0v[4], p1v[4];
#pragma unroll
        for (int r = 0; r < 4; ++r) {
          p0v[r] = __builtin_amdgcn_exp2f(s0[r]);
          p1v[r] = __builtin_amdgcn_exp2f(s1[r]);
        }
        u16x8 pw;
#pragma unroll
        for (int r = 0; r < 4; ++r) { pw[r] = f2bf(p0v[r]); pw[4 + r] = f2bf(p1v[r]); }
        const bf16x8 pb = __builtin_bit_cast(bf16x8, pw);
        __builtin_amdgcn_s_setprio(1);
#pragma unroll
        for (int n = 0; n < 4; ++n) o[qs][n] = MFMA16(va[n], pb, o[qs][n]);
        o4[qs] = MFMA16(ones, pb, o4[qs]);   // row-sums per q-subtile
        __builtin_amdgcn_s_setprio(0);
      }
    }

    __syncthreads();   // drains vmcnt (staging done) + orders LDS reuse
    cur ^= 1;
  }

  const int qg = ks * N_TOK + q0;
#pragma unroll
  for (int qs = 0; qs < 2; ++qs) {
#pragma unroll
    for (int n = 0; n < 4; ++n) {
      u16x4 ov;
#pragma unroll
      for (int r = 0; r < 4; ++r) ov[r] = f2bf(o[qs][n][r]);
      *(u16x4*)&Opart[(size_t)(qg + qs * 16 + lr) * CI + n * 16 + 4 * g] = ov;
    }
    if (lane < 16) Lpart[qg + qs * 16 + lr] = o4[qs][0];
  }
}

// ---------------------------------------------------------------------------
// K3 (fused): PARALLEL combine (8 threads per token) + 2nd softmax -> y in
// LDS -> output GEMM + bias + residual. (R16-passing version, SPL-templated)
// ---------------------------------------------------------------------------
template <int SPL>
__global__ __launch_bounds__(256) void k3_fused(
    const u16* __restrict__ Opart, const float* __restrict__ Lpart,
    const float* __restrict__ ow, const float* __restrict__ ob,
    const float* __restrict__ x, float* __restrict__ out)
{
  __shared__ u16 ylds[32 * 72];
  const int tid = threadIdx.x;
  const int w = tid >> 6, lane = tid & 63;
  const int lr = lane & 15, lg = lane >> 4;
  const int p0 = blockIdx.x * 32;

  // ---- phase 1: combine + 2nd softmax, 8 threads per token ----
  {
    const int tok = tid >> 3, dj = (tid & 7) * 8;
    const int q = p0 + tok;

    float L = 0.f;
    float acc[8];
#pragma unroll
    for (int j = 0; j < 8; ++j) acc[j] = 0.f;
#pragma unroll
    for (int k = 0; k < SPL; ++k) {
      L += Lpart[k * N_TOK + q];
      u32x4 v = *(const u32x4*)&Opart[(size_t)(k * N_TOK + q) * CI + dj];
      const u16* pv = (const u16*)&v;
#pragma unroll
      for (int j = 0; j < 8; ++j) acc[j] += bf2f(pv[j]);
    }
    const float invL = 1.f / L;
    float ypre[8];
#pragma unroll
    for (int j = 0; j < 8; ++j) ypre[j] = acc[j] * invL;

    float mx = ypre[0];
#pragma unroll
    for (int j = 1; j < 8; ++j) mx = fmaxf(mx, ypre[j]);
    mx = fmaxf(mx, __shfl_xor(mx, 1, 64));
    mx = fmaxf(mx, __shfl_xor(mx, 2, 64));
    mx = fmaxf(mx, __shfl_xor(mx, 4, 64));

    float e[8], s = 0.f;
#pragma unroll
    for (int j = 0; j < 8; ++j) {
      e[j] = __builtin_amdgcn_exp2f((ypre[j] - mx) * L2E);
      s += e[j];
    }
    s += __shfl_xor(s, 1, 64);
    s += __shfl_xor(s, 2, 64);
    s += __shfl_xor(s, 4, 64);
    const float inv = 1.f / s;

    u16x8 yv;
#pragma unroll
    for (int j = 0; j < 8; ++j) yv[j] = f2bf(e[j] * inv);
    *(u16x8*)&ylds[tok * 72 + dj] = yv;   // 16B store, row stride 144B (16-aligned)
  }
  __syncthreads();

  // ---- phase 2: output GEMM (y from LDS stride 72) ----
  bf16x8 yb[2][2];
#pragma unroll
  for (int nt = 0; nt < 2; ++nt)
#pragma unroll
    for (int kc = 0; kc < 2; ++kc)
      yb[nt][kc] = load_bf8(&ylds[(nt * 16 + lr) * 72 + kc * 32 + lg * 8]);

#pragma unroll
  for (int mt = 0; mt < 2; ++mt) {
    bf16x8 af[2];
#pragma unroll
    for (int kc = 0; kc < 2; ++kc) {
      const float* src = ow + (w * 32 + mt * 16 + lr) * CI + kc * 32 + lg * 8;
      float f[8];
#pragma unroll
      for (int j = 0; j < 8; ++j) f[j] = src[j];
      af[kc] = pack8(f);
    }
#pragma unroll
    for (int nt = 0; nt < 2; ++nt) {
      f32x4 acc = f32x4{0.f, 0.f, 0.f, 0.f};
      acc = MFMA16(af[0], yb[nt][0], acc);
      acc = MFMA16(af[1], yb[nt][1], acc);
#pragma unroll
      for (int r = 0; r < 4; ++r) {
        const int c = w * 32 + mt * 16 + lg * 4 + r;
        const int p = p0 + nt * 16 + lr;
        out[(size_t)c * N_TOK + p] = acc[r] + ob[c] + x[(size_t)c * N_TOK + p];
      }
    }
  }
}

extern "C" void kernel_launch(void* const* d_in, const int* in_sizes, int n_in,
                              void* d_out, int out_size, void* d_ws, size_t ws_size,
                              hipStream_t stream) {
  const float* x  = (const float*)d_in[0];
  const float* tw = (const float*)d_in[1];
  const float* tb = (const float*)d_in[2];
  const float* pw = (const float*)d_in[3];
  const float* pb = (const float*)d_in[4];
  const float* gw = (const float*)d_in[5];
  const float* gb = (const float*)d_in[6];
  const float* ow = (const float*)d_in[7];
  const float* ob = (const float*)d_in[8];
  float* out = (float*)d_out;

  char* ws = (char*)d_ws;
  u16* thetaF = (u16*)(ws);
  u16* phiF   = (u16*)(ws + 1179648);
  u16* vF     = (u16*)(ws + 2 * 1179648);
  u16* Op     = (u16*)(ws + 4 * 1179648);

  const size_t opOff = 4 * 1179648;
  const size_t need24 = opOff + (size_t)24 * N_TOK * CI * 2 + (size_t)24 * N_TOK * 4;

  hipLaunchKernelGGL(k1_proj, dim3(144, 3), dim3(256), 0, stream,
                     x, tw, tb, pw, pb, gw, gb, thetaF, phiF, vF);

  if (ws_size >= need24) {
    float* Lp = (float*)(ws + opOff + (size_t)24 * N_TOK * CI * 2);
    hipLaunchKernelGGL((k2_flash<24>), dim3(72 * 24), dim3(256), 0, stream,
                       thetaF, phiF, vF, Op, Lp);
    hipLaunchKernelGGL((k3_fused<24>), dim3(288), dim3(256), 0, stream,
                       Op, Lp, ow, ob, x, out);
  } else {
    float* Lp = (float*)(ws + opOff + (size_t)8 * N_TOK * CI * 2);
    hipLaunchKernelGGL((k2_flash<8>), dim3(72 * 8), dim3(256), 0, stream,
                       thetaF, phiF, vF, Op, Lp);
    hipLaunchKernelGGL((k3_fused<8>), dim3(288), dim3(256), 0, stream,
                       Op, Lp, ow, ob, x, out);
  }
}